// Round 14
// baseline (51.823 us; speedup 1.0000x reference)
//
#include <hip/hip_runtime.h>

// DynamicMaskHead, barrier-free rolling-window kernel (R12 structure) with
// SCALAR global weight reads (R13 fix). One thread owns one input COLUMN and
// walks TR+2 rows: per-px MLP -> 3-row register logit window -> x-neighbors
// via wave shuffles -> 16 sigmoids -> 4 float4 stores PER ITERATION.
// Zero LDS, zero barriers: store issue is spread uniformly over the kernel
// lifetime so HBM writes drain under MLP/trans compute (phase-structured
// variants R7-R13 all plateau at ~31us = serial sum of compute + stores;
// R12's regression was per-px LDS weight reads, ~+18us on the LDS pipe --
// with block-uniform global reads the weights ride the scalar cache).
// Wave covers 64 cols, emits 62 (lanes 0,63 halo); 3 waves cover W=152.
// Shapes fixed by harness: N=2, Cin=8, H=100, W=152, n_inst=100, stride=8.

#define CIN 8
#define HH 100
#define WW 152
#define HWSZ (HH * WW)
#define NI 100
#define OH (HH * 4)
#define OW (WW * 4)
#define TR 10                              // emitted rows per block (HH%TR==0)
#define BLOCK 192                          // 3 waves

__device__ __forceinline__ float fast_rcp(float x) {
    return __builtin_amdgcn_rcpf(x);       // v_rcp_f32, ~1 ulp
}

__device__ __forceinline__ float fast_mish(float x) {
    // mish(x) = x * n/(n+2), n = e(e+2), e = exp(x). Clamp only the exp arg:
    // for x>20, n/(n+2)==1 in fp32 -> formula stays exact, branchless.
    float e = __expf(fminf(x, 20.f));
    float n = e * (e + 2.f);
    return x * n * fast_rcp(n + 2.f);
}

__device__ __forceinline__ float fast_sigmoid(float z) {
    return fast_rcp(1.f + __expf(-z));
}

__global__ void __launch_bounds__(BLOCK)
fused_mask_head_kernel(const float* __restrict__ mask_feats,
                       const float* __restrict__ params,
                       const float* __restrict__ inst_locs,
                       const int* __restrict__ im_inds,
                       const int* __restrict__ fpn_levels,
                       const int* __restrict__ stride_ptr,
                       float* __restrict__ out) {
    const int inst = blockIdx.y;
    const int r0 = blockIdx.x * TR;
    const int t = threadIdx.x;

    // block-uniform weight pointer -> compiler scalarizes to s_load (SGPR
    // operands, scalar cache). No LDS staging, no barrier.
    const float* __restrict__ P = params + inst * 169;

    const int wave = t >> 6;
    const int lane = t & 63;
    const int c = wave * 62 + lane - 1;     // center column (may be OOB on halo lanes)
    const int colc = min(max(c, 0), WW - 1);
    const bool emit_ok = (lane >= 1) && (lane <= 62) && (c >= 0) && (c < WW);

    // block-uniform instance scalars
    const int stride = stride_ptr[0];
    const float half = (float)(stride / 2);
    const float soi_tab[5] = {64.f, 128.f, 256.f, 512.f, 1024.f};
    const float inv_soi = 1.f / soi_tab[fpn_levels[inst]];
    const float lx = inst_locs[inst * 2 + 0];
    const float ly = inst_locs[inst * 2 + 1];
    const float xrel = (lx - (float)(colc * stride) - half) * inv_soi;  // col term, fixed
    const float* fcol = mask_feats + (size_t)im_inds[inst] * CIN * HWSZ + colc;
    float* const obase = out + (size_t)inst * (OH * OW);

    // rolling 3-row logit window, each row as (left, center, right)
    float pl = 0.f, pm = 0.f, prr = 0.f;
    float clft = 0.f, cm = 0.f, crt = 0.f;
    float nl = 0.f, nm = 0.f, nr = 0.f;

    // feature prefetch for first row
    float f[CIN], fn[CIN];
    {
        const int rr = min(max(r0 - 1, 0), HH - 1);
        const float* fr = fcol + rr * WW;
#pragma unroll
        for (int ch = 0; ch < CIN; ++ch) f[ch] = fr[(size_t)ch * HWSZ];
    }

    for (int i = 0; i < TR + 2; ++i) {
        const int rU = r0 + i - 1;                       // unclamped row being computed
        const int rr = min(max(rU, 0), HH - 1);

        // prefetch next row's features (hidden under this row's MLP)
        if (i < TR + 1) {
            const int rn = min(max(rU + 1, 0), HH - 1);
            const float* fr = fcol + rn * WW;
#pragma unroll
            for (int ch = 0; ch < CIN; ++ch) fn[ch] = fr[(size_t)ch * HWSZ];
        }

        // ---- MLP for (rr, colc): 10 -> 8 -> 8 -> 1, mish; weights via SGPR ----
        const float relY = (ly - (float)(rr * stride) - half) * inv_soi;
        float h1[8];
#pragma unroll
        for (int o = 0; o < 8; ++o) {
            float acc = fmaf(P[o * 10 + 0], xrel, fmaf(P[o * 10 + 1], relY, P[152 + o]));
#pragma unroll
            for (int ch = 0; ch < CIN; ++ch) acc = fmaf(P[o * 10 + 2 + ch], f[ch], acc);
            h1[o] = fast_mish(acc);
        }
        float L = P[168];
#pragma unroll
        for (int o = 0; o < 8; ++o) {
            float acc = P[160 + o];
#pragma unroll
            for (int ii = 0; ii < 8; ++ii) acc = fmaf(P[80 + o * 8 + ii], h1[ii], acc);
            L = fmaf(P[144 + o], fast_mish(acc), L);
        }

        // neighbors via wave shuffle (halo lanes 0/63 never emit)
        const float Ll = __shfl_up(L, 1);
        const float Lr = __shfl_down(L, 1);

        // shift window
        pl = clft; pm = cm; prr = crt;
        clft = nl;  cm = nm;  crt = nr;
        nl = Ll;  nm = L;   nr = Lr;

        // ---- emit 4x4 output block for rg = rU-1 once window is full ----
        if (i >= 2 && emit_ok) {
            const int rg = rU - 1;                       // in [r0, r0+TR-1]
            // horizontal interp per window row: x-samples k=0..3
            // k0=.5(L+C) k1=.25L+.75C k2=C k3=.75C+.25R
            float h0s[4], h1s[4], h2s[4];
            h0s[0] = 0.5f * (pl + pm);  h0s[1] = fmaf(0.25f, pl, 0.75f * pm);  h0s[2] = pm; h0s[3] = fmaf(0.25f, prr, 0.75f * pm);
            h1s[0] = 0.5f * (clft + cm); h1s[1] = fmaf(0.25f, clft, 0.75f * cm); h1s[2] = cm; h1s[3] = fmaf(0.25f, crt, 0.75f * cm);
            h2s[0] = 0.5f * (nl + nm);  h2s[1] = fmaf(0.25f, nl, 0.75f * nm);  h2s[2] = nm; h2s[3] = fmaf(0.25f, nr, 0.75f * nm);

            float* O = obase + (size_t)(4 * rg) * OW + 4 * c;
            float4 row;
            // k=0: .5 prev + .5 cur
            row.x = fast_sigmoid(0.5f * (h0s[0] + h1s[0]));
            row.y = fast_sigmoid(0.5f * (h0s[1] + h1s[1]));
            row.z = fast_sigmoid(0.5f * (h0s[2] + h1s[2]));
            row.w = fast_sigmoid(0.5f * (h0s[3] + h1s[3]));
            *reinterpret_cast<float4*>(O) = row;
            // k=1: .25 prev + .75 cur
            row.x = fast_sigmoid(fmaf(0.25f, h0s[0], 0.75f * h1s[0]));
            row.y = fast_sigmoid(fmaf(0.25f, h0s[1], 0.75f * h1s[1]));
            row.z = fast_sigmoid(fmaf(0.25f, h0s[2], 0.75f * h1s[2]));
            row.w = fast_sigmoid(fmaf(0.25f, h0s[3], 0.75f * h1s[3]));
            *reinterpret_cast<float4*>(O + OW) = row;
            // k=2: cur
            row.x = fast_sigmoid(h1s[0]);
            row.y = fast_sigmoid(h1s[1]);
            row.z = fast_sigmoid(h1s[2]);
            row.w = fast_sigmoid(h1s[3]);
            *reinterpret_cast<float4*>(O + 2 * OW) = row;
            // k=3: .75 cur + .25 next
            row.x = fast_sigmoid(fmaf(0.25f, h2s[0], 0.75f * h1s[0]));
            row.y = fast_sigmoid(fmaf(0.25f, h2s[1], 0.75f * h1s[1]));
            row.z = fast_sigmoid(fmaf(0.25f, h2s[2], 0.75f * h1s[2]));
            row.w = fast_sigmoid(fmaf(0.25f, h2s[3], 0.75f * h1s[3]));
            *reinterpret_cast<float4*>(O + 3 * OW) = row;
        }

        // rotate prefetched features in
#pragma unroll
        for (int ch = 0; ch < CIN; ++ch) f[ch] = fn[ch];
    }
}

extern "C" void kernel_launch(void* const* d_in, const int* in_sizes, int n_in,
                              void* d_out, int out_size, void* d_ws, size_t ws_size,
                              hipStream_t stream) {
    const float* mask_feats = (const float*)d_in[0];
    const float* params     = (const float*)d_in[1];
    const float* inst_locs  = (const float*)d_in[2];
    const int*   im_inds    = (const int*)d_in[3];
    const int*   fpn_levels = (const int*)d_in[4];
    const int*   stride_ptr = (const int*)d_in[5];
    float* out = (float*)d_out;

    dim3 block(BLOCK);
    dim3 grid(HH / TR, NI);                // 10 x 100 = 1000 blocks
    fused_mask_head_kernel<<<grid, block, 0, stream>>>(
        mask_feats, params, inst_locs, im_inds, fpn_levels, stride_ptr, out);
}

// Round 15
// 32.117 us; speedup vs baseline: 1.6136x; 1.6136x over previous
//
#include <hip/hip_runtime.h>

// DynamicMaskHead, fused (R13 structure) + packed-f32 arithmetic (R15).
// Counters (R14) proved the op is ISSUE-bound (VALUBusy 53%, HBM 20%), so
// this round halves issue slots: float2 ext-vectors over pixel pairs form
// v_pk_fma_f32 (VOP3P) in the MLP chains; sigmoid's exp scale/sign is folded
// into w3/b3 (tile holds L' = -log2e*logit; bilinear commutes; sigmoid =
// rcp(1+2^z')); mish uses x - 2x*rcp((e+1)^2+1).
// Block = (instance, 10-row chunk), 512 threads, one 4-px quad per thread,
// straight-line MLP (loop-wrapping spills: R8). Weights via block-uniform
// global reads -> s_load/SGPR (R13). Upsample reads 3x3 from LDS tile.
// Shapes fixed by harness: N=2, Cin=8, H=100, W=152, n_inst=100, stride=8.

#define CIN 8
#define HH 100
#define WW 152
#define HWSZ (HH * WW)
#define NI 100
#define OH (HH * 4)
#define OW (WW * 4)
#define TROWS 10                           // input rows per block (HH%TROWS==0)
#define LROWS (TROWS + 2)                  // + halo
#define QPR (WW / 4)                       // 38 quads per row
#define NQUADS (LROWS * QPR)               // 456 <= 512: one quad per thread
#define UITEMS (TROWS * WW)                // 1520 upsample work items
#define BLOCK 512
#define NLOG2E (-1.44269504f)              // -log2(e), sigmoid fold factor

typedef float v2f __attribute__((ext_vector_type(2)));

__device__ __forceinline__ float fast_rcp(float x) {
    return __builtin_amdgcn_rcpf(x);       // v_rcp_f32, ~1 ulp
}

// mish on a pixel pair. mish(x) = x*n/(n+2), n = e(e+2), e = exp(x)
//                              = x - 2x*rcp((e+1)^2 + 1)   [n+2 = (e+1)^2+1]
// exp arg clamped at 20 (for x>20 the factor is 1.0 in fp32) -> branchless.
__device__ __forceinline__ v2f mish2(v2f x) {
    v2f xc = __builtin_elementwise_min(x, (v2f)20.f);
    v2f e;
    e.x = __expf(xc.x);
    e.y = __expf(xc.y);
    v2f t = e + 1.f;
    v2f d = t * t + 1.f;
    v2f r;
    r.x = fast_rcp(d.x);
    r.y = fast_rcp(d.y);
    return x - (x + x) * r;
}

// sigmoid in folded space: z' = -log2e * logit  ->  sigma = 1/(1+2^z')
__device__ __forceinline__ float fold_sigmoid(float zp) {
    return fast_rcp(1.f + exp2f(zp));      // exp2f -> bare v_exp_f32
}

__global__ void __launch_bounds__(BLOCK, 2)
fused_mask_head_kernel(const float* __restrict__ mask_feats,
                       const float* __restrict__ params,
                       const float* __restrict__ inst_locs,
                       const int* __restrict__ im_inds,
                       const int* __restrict__ fpn_levels,
                       const int* __restrict__ stride_ptr,
                       float* __restrict__ out) {
    __shared__ float tile[LROWS][WW];      // folded logits L' (rows r0-1..r0+TROWS)

    const int inst = blockIdx.y;
    const int r0 = blockIdx.x * TROWS;
    const int t = threadIdx.x;

    // block-uniform weight pointer -> scalar loads, SGPR operands
    const float* __restrict__ P = params + inst * 169;

    const int stride = stride_ptr[0];
    const float half = (float)(stride / 2);
    const float soi_tab[5] = {64.f, 128.f, 256.f, 512.f, 1024.f};
    const float inv_soi = 1.f / soi_tab[fpn_levels[inst]];
    const float lx = inst_locs[inst * 2 + 0];
    const float ly = inst_locs[inst * 2 + 1];
    const float dx = -(float)stride * inv_soi;
    const float* fbase = mask_feats + (size_t)im_inds[inst] * CIN * HWSZ;

    // ------------- MLP phase: one 4-px quad per thread, straight-line -------------
    if (t < NQUADS) {
        const int lr  = t / QPR;
        const int qc  = t - lr * QPR;
        const int col = qc * 4;
        const int gr  = min(max(r0 + lr - 1, 0), HH - 1);

        const float relY = (ly - (float)(gr * stride) - half) * inv_soi;
        const float x0b  = (lx - (float)(col * stride) - half) * inv_soi;
        const v2f xs01 = {x0b, x0b + dx};
        const v2f xs23 = {x0b + 2.f * dx, x0b + 3.f * dx};

        const float* fb = fbase + gr * WW + col;
        v2f f01[CIN], f23[CIN];
#pragma unroll
        for (int c = 0; c < CIN; ++c) {
            float4 ff = *reinterpret_cast<const float4*>(fb + (size_t)c * HWSZ);
            f01[c] = (v2f){ff.x, ff.y};
            f23[c] = (v2f){ff.z, ff.w};
        }

        // layer 1: 10 -> 8, mish (w1[o][i]=P[o*10+i], b1=P[152+o]); pk chains
        v2f h1p[8][2];
#pragma unroll
        for (int o = 0; o < 8; ++o) {
            const float w0 = P[o * 10 + 0], w1 = P[o * 10 + 1];
            const float rt = fmaf(w1, relY, P[152 + o]);   // uniform across j
            v2f a01 = (v2f)rt + w0 * xs01;
            v2f a23 = (v2f)rt + w0 * xs23;
#pragma unroll
            for (int c = 0; c < CIN; ++c) {
                const float wc = P[o * 10 + 2 + c];
                a01 = wc * f01[c] + a01;
                a23 = wc * f23[c] + a23;
            }
            h1p[o][0] = mish2(a01);
            h1p[o][1] = mish2(a23);
        }

        // layers 2+3 fused, with sigmoid fold on w3/b3:
        //   L'[j] = (-log2e)*(b3 + sum_o w3[o]*mish(w2[o]·h1+b2[o]))
        v2f lo01 = (v2f)(NLOG2E * P[168]);
        v2f lo23 = lo01;
#pragma unroll
        for (int o = 0; o < 8; ++o) {
            const float b2 = P[160 + o];
            v2f a01 = (v2f)b2;
            v2f a23 = (v2f)b2;
#pragma unroll
            for (int i = 0; i < 8; ++i) {
                const float wi = P[80 + o * 8 + i];
                a01 = wi * h1p[i][0] + a01;
                a23 = wi * h1p[i][1] + a23;
            }
            const float w3p = NLOG2E * P[144 + o];
            lo01 = w3p * mish2(a01) + lo01;
            lo23 = w3p * mish2(a23) + lo23;
        }
        *reinterpret_cast<float4*>(&tile[lr][col]) =
            make_float4(lo01.x, lo01.y, lo23.x, lo23.y);
    }
    __syncthreads();

    // ------------- upsample phase: 1520 4x4 blocks, from LDS tile -------------
    // Interp in folded space (linear -> commutes). Output row Y=4r+k weights:
    //   k=0: .5 prev + .5 cur | k=1: .25 prev + .75 cur | k=2: cur | k=3: .75 cur + .25 next
    for (int b = t; b < UITEMS; b += BLOCK) {
        const int rg = b / WW;
        const int cg = b - rg * WW;
        const int lr = rg + 1;
        const int gm1 = max(cg - 1, 0), gp1 = min(cg + 1, WW - 1);

        const float v00 = tile[lr - 1][gm1], v01 = tile[lr - 1][cg], v02 = tile[lr - 1][gp1];
        const float v10 = tile[lr    ][gm1], v11 = tile[lr    ][cg], v12 = tile[lr    ][gp1];
        const float v20 = tile[lr + 1][gm1], v21 = tile[lr + 1][cg], v22 = tile[lr + 1][gp1];

        float h0[4], h1[4], h2[4];
        h0[0] = 0.5f * (v00 + v01); h0[1] = fmaf(0.25f, v00, 0.75f * v01); h0[2] = v01; h0[3] = fmaf(0.25f, v02, 0.75f * v01);
        h1[0] = 0.5f * (v10 + v11); h1[1] = fmaf(0.25f, v10, 0.75f * v11); h1[2] = v11; h1[3] = fmaf(0.25f, v12, 0.75f * v11);
        h2[0] = 0.5f * (v20 + v21); h2[1] = fmaf(0.25f, v20, 0.75f * v21); h2[2] = v21; h2[3] = fmaf(0.25f, v22, 0.75f * v21);

        float* O = out + (size_t)inst * (OH * OW) + (size_t)(4 * (r0 + rg)) * OW + 4 * cg;
        float4 row;
        row.x = fold_sigmoid(0.5f * (h0[0] + h1[0]));
        row.y = fold_sigmoid(0.5f * (h0[1] + h1[1]));
        row.z = fold_sigmoid(0.5f * (h0[2] + h1[2]));
        row.w = fold_sigmoid(0.5f * (h0[3] + h1[3]));
        *reinterpret_cast<float4*>(O) = row;
        row.x = fold_sigmoid(fmaf(0.25f, h0[0], 0.75f * h1[0]));
        row.y = fold_sigmoid(fmaf(0.25f, h0[1], 0.75f * h1[1]));
        row.z = fold_sigmoid(fmaf(0.25f, h0[2], 0.75f * h1[2]));
        row.w = fold_sigmoid(fmaf(0.25f, h0[3], 0.75f * h1[3]));
        *reinterpret_cast<float4*>(O + OW) = row;
        row.x = fold_sigmoid(h1[0]);
        row.y = fold_sigmoid(h1[1]);
        row.z = fold_sigmoid(h1[2]);
        row.w = fold_sigmoid(h1[3]);
        *reinterpret_cast<float4*>(O + 2 * OW) = row;
        row.x = fold_sigmoid(fmaf(0.25f, h2[0], 0.75f * h1[0]));
        row.y = fold_sigmoid(fmaf(0.25f, h2[1], 0.75f * h1[1]));
        row.z = fold_sigmoid(fmaf(0.25f, h2[2], 0.75f * h1[2]));
        row.w = fold_sigmoid(fmaf(0.25f, h2[3], 0.75f * h1[3]));
        *reinterpret_cast<float4*>(O + 3 * OW) = row;
    }
}

extern "C" void kernel_launch(void* const* d_in, const int* in_sizes, int n_in,
                              void* d_out, int out_size, void* d_ws, size_t ws_size,
                              hipStream_t stream) {
    const float* mask_feats = (const float*)d_in[0];
    const float* params     = (const float*)d_in[1];
    const float* inst_locs  = (const float*)d_in[2];
    const int*   im_inds    = (const int*)d_in[3];
    const int*   fpn_levels = (const int*)d_in[4];
    const int*   stride_ptr = (const int*)d_in[5];
    float* out = (float*)d_out;

    dim3 block(BLOCK);
    dim3 grid(HH / TROWS, NI);             // 10 x 100 = 1000 blocks
    fused_mask_head_kernel<<<grid, block, 0, stream>>>(
        mask_feats, params, inst_locs, im_inds, fpn_levels, stride_ptr, out);
}